// Round 2
// baseline (1023.459 us; speedup 1.0000x reference)
//
#include <hip/hip_runtime.h>
#include <hip/hip_bf16.h>

#define B_ 4
#define S_ 128
#define D_ 512
#define H_ 8
#define DH_ 64
#define F_ 2048
#define R_ 8
#define BS_ (B_ * S_)
#define BSD_ (BS_ * D_)
#define E_ 262144          // 512*512
#define NBLK 512           // persistent blocks; 2/CU guaranteed by launch_bounds(256,2)

typedef __attribute__((ext_vector_type(8))) short short8;
typedef __attribute__((ext_vector_type(4))) float f32x4;
typedef __attribute__((ext_vector_type(4))) unsigned short ushort4v;

// fp32 -> bf16 hi (RNE) + bf16 lo (RNE of exact residual)
__device__ __forceinline__ void split2(float a, unsigned short& h, unsigned short& l) {
    unsigned u = __float_as_uint(a);
    unsigned hr = (u + 0x7FFFu + ((u >> 16) & 1u)) >> 16;
    h = (unsigned short)hr;
    float lo = a - __uint_as_float(hr << 16);
    unsigned u2 = __float_as_uint(lo);
    l = (unsigned short)((u2 + 0x7FFFu + ((u2 >> 16) & 1u)) >> 16);
}

#define RP 40   // LDS row pitch in ushorts (32 + 8 pad)

struct GemmLds {                       // double-buffered: [buf][hi/lo][row][col]
    unsigned short A[2][2][64][RP];
    unsigned short B[2][2][64][RP];
};                                     // 40960 bytes

union SMem {
    GemmLds g;
    float tr[32][33];
    struct { float qsm[4][DH_]; float psm[4][S_]; } at;
    struct { float acc[R_ * D_]; int rl[S_]; } mb;
    float red[256];
};

struct TDesc { const float* s; unsigned short* h; unsigned short* l; int K; int N; int off; };

struct MegaArgs {
    const float *x, *ln1_g, *ln1_b;
    const float *bq, *bk, *bv, *bo, *b1, *b2;
    const float *rc_b1, *rc_w2, *rc_b2, *s2n_b, *ln2_g, *ln2_b;
    TDesc td[10];
    const unsigned short *qkv_h, *qkv_l, *wo_h, *wo_l, *w1_h, *w1_l, *w2_h, *w2_l;
    const unsigned short *rc_h, *rc_l, *kg_h, *kg_l, *s2_h, *s2_l;
    unsigned short *xn_h, *xn_l, *ctx_h, *ctx_l, *ao_h, *ao_l, *hid_h, *hid_l;
    unsigned short *nu_h, *nu_l, *mb_h, *mb_l, *rs_h, *rs_l;
    float *attn, *q, *apart, *nu, *y, *part4, *part8;
    int *rel, *ecount, *elist, *flags, *gen;
    float *outp;
};

// ---------------- grid barrier (all NBLK blocks co-resident) ----------------
// Every wave drains its own stores + wb L2 via __threadfence before arriving.
// flags[bid*16] monotone phase; block 0 scans, publishes gen; readers fence (inv L2/L1).
__device__ __forceinline__ void grid_barrier(int* flags, int* gen, int phase) {
    __threadfence();                 // per-wave: vmcnt drain + L2 writeback (agent scope)
    __syncthreads();
    if (threadIdx.x == 0)
        __hip_atomic_store(&flags[blockIdx.x * 16], phase, __ATOMIC_RELEASE, __HIP_MEMORY_SCOPE_AGENT);
    if (blockIdx.x == 0) {
        if (threadIdx.x < 64) {
#pragma unroll
            for (int s = 0; s < NBLK / 64; ++s) {
                int slot = (threadIdx.x + s * 64) * 16;
                while (__hip_atomic_load(&flags[slot], __ATOMIC_RELAXED, __HIP_MEMORY_SCOPE_AGENT) < phase) {}
            }
        }
        __syncthreads();
        if (threadIdx.x == 0) {
            __threadfence();
            __hip_atomic_store(gen, phase, __ATOMIC_RELEASE, __HIP_MEMORY_SCOPE_AGENT);
        }
    }
    if (threadIdx.x == 0) {
        while (__hip_atomic_load(gen, __ATOMIC_RELAXED, __HIP_MEMORY_SCOPE_AGENT) < phase) {}
        __threadfence();             // acquire: invalidate L1 + this XCD's L2
    }
    __syncthreads();
}

// ---------------- GEMM tile: double-buffered LDS + 1-step register prefetch ----------------
__device__ void do_gemm_tile(const unsigned short* __restrict__ Ath,
                             const unsigned short* __restrict__ Atl,
                             const unsigned short* __restrict__ Bth,
                             const unsigned short* __restrict__ Btl,
                             const float* __restrict__ bias,
                             float* __restrict__ Cf,
                             unsigned short* __restrict__ Ch,
                             unsigned short* __restrict__ Cl,
                             int N, int K, int kStart, int nsteps, int relu,
                             int rowBase, int colBase, GemmLds* L) {
    int tid = threadIdx.x;
    int w = tid >> 6, lane = tid & 63;
    int lm = lane & 15, quad = lane >> 4;
    int wm = (w & 1) * 32, wn = (w >> 1) * 32;
    int rS = tid >> 2, kcS = (tid & 3) * 8;
    f32x4 acc[2][2] = {};
    size_t aoff = (size_t)(rowBase + rS) * K + kStart + kcS;
    size_t boff = (size_t)(colBase + rS) * K + kStart + kcS;
    short8 rah = *(const short8*)&Ath[aoff];
    short8 ral = *(const short8*)&Atl[aoff];
    short8 rbh = *(const short8*)&Bth[boff];
    short8 rbl = *(const short8*)&Btl[boff];
    for (int s = 0; s < nsteps; ++s) {
        int p = s & 1;
        *(short8*)&L->A[p][0][rS][kcS] = rah;
        *(short8*)&L->A[p][1][rS][kcS] = ral;
        *(short8*)&L->B[p][0][rS][kcS] = rbh;
        *(short8*)&L->B[p][1][rS][kcS] = rbl;
        __syncthreads();
        if (s + 1 < nsteps) {       // prefetch next k-step; latency hides under ds_read+MFMA
            size_t ao = aoff + (size_t)(s + 1) * 32;
            size_t bo = boff + (size_t)(s + 1) * 32;
            rah = *(const short8*)&Ath[ao];
            ral = *(const short8*)&Atl[ao];
            rbh = *(const short8*)&Bth[bo];
            rbl = *(const short8*)&Btl[bo];
        }
        short8 ah[2], al[2], bh[2], bl[2];
#pragma unroll
        for (int t = 0; t < 2; ++t) {
            ah[t] = *(const short8*)&L->A[p][0][wm + t * 16 + lm][quad * 8];
            al[t] = *(const short8*)&L->A[p][1][wm + t * 16 + lm][quad * 8];
            bh[t] = *(const short8*)&L->B[p][0][wn + t * 16 + lm][quad * 8];
            bl[t] = *(const short8*)&L->B[p][1][wn + t * 16 + lm][quad * 8];
        }
#pragma unroll
        for (int tm = 0; tm < 2; ++tm)
#pragma unroll
            for (int tn = 0; tn < 2; ++tn) {
                acc[tm][tn] = __builtin_amdgcn_mfma_f32_16x16x32_bf16(ah[tm], bh[tn], acc[tm][tn], 0, 0, 0);
                acc[tm][tn] = __builtin_amdgcn_mfma_f32_16x16x32_bf16(ah[tm], bl[tn], acc[tm][tn], 0, 0, 0);
                acc[tm][tn] = __builtin_amdgcn_mfma_f32_16x16x32_bf16(al[tm], bh[tn], acc[tm][tn], 0, 0, 0);
            }
    }
    __syncthreads();
#pragma unroll
    for (int tm = 0; tm < 2; ++tm)
#pragma unroll
        for (int tn = 0; tn < 2; ++tn) {
            int col = colBase + wn + tn * 16 + lm;
            float bi = bias ? bias[col] : 0.f;
#pragma unroll
            for (int r = 0; r < 4; ++r) {
                int row = rowBase + wm + tm * 16 + quad * 4 + r;
                float v = acc[tm][tn][r] + bi;
                if (relu) v = fmaxf(v, 0.f);
                size_t o = (size_t)row * N + col;
                if (Cf) Cf[o] = v;
                if (Ch) {
                    unsigned short sh, sl;
                    split2(v, sh, sl);
                    Ch[o] = sh; Cl[o] = sl;
                }
            }
        }
}

// ---------------- stage helpers ----------------
__device__ void do_transpose(const MegaArgs& a, int t0, SMem& sm) {
    TDesc dd = a.td[0];
#pragma unroll
    for (int i = 1; i < 10; ++i) if (t0 >= a.td[i].off) dd = a.td[i];
    int t = t0 - dd.off;
    int ntk = dd.K / 32;
    int tk = t % ntk, tn = t / ntk;
    int k0 = tk * 32, n0 = tn * 32;
    int col = threadIdx.x & 31, rg = threadIdx.x >> 5;
#pragma unroll
    for (int i = 0; i < 4; ++i)
        sm.tr[rg * 4 + i][col] = dd.s[(size_t)(k0 + rg * 4 + i) * dd.N + n0 + col];
    __syncthreads();
#pragma unroll
    for (int i = 0; i < 4; ++i) {
        int n = n0 + rg * 4 + i, k = k0 + col;
        unsigned short h, l;
        split2(sm.tr[col][rg * 4 + i], h, l);
        dd.h[(size_t)n * dd.K + k] = h;
        dd.l[(size_t)n * dd.K + k] = l;
    }
}

__device__ void do_ln1row(const MegaArgs& a, int row, SMem& sm) {
    int t = threadIdx.x;
    const float* xr = a.x + (size_t)row * D_;
    float v0 = xr[t], v1 = xr[t + 256];
    sm.red[t] = v0 + v1;
    __syncthreads();
    for (int off = 128; off > 0; off >>= 1) { if (t < off) sm.red[t] += sm.red[t + off]; __syncthreads(); }
    float mean = sm.red[0] * (1.0f / D_);
    __syncthreads();
    float d0 = v0 - mean, d1 = v1 - mean;
    sm.red[t] = d0 * d0 + d1 * d1;
    __syncthreads();
    for (int off = 128; off > 0; off >>= 1) { if (t < off) sm.red[t] += sm.red[t + off]; __syncthreads(); }
    float rs = rsqrtf(sm.red[0] * (1.0f / D_) + 1e-5f);
    float o0 = d0 * rs * a.ln1_g[t] + a.ln1_b[t];
    float o1 = d1 * rs * a.ln1_g[t + 256] + a.ln1_b[t + 256];
    unsigned short h, l;
    split2(o0, h, l); a.xn_h[(size_t)row * D_ + t] = h;       a.xn_l[(size_t)row * D_ + t] = l;
    split2(o1, h, l); a.xn_h[(size_t)row * D_ + t + 256] = h; a.xn_l[(size_t)row * D_ + t + 256] = l;
}

__device__ void do_attn(const MegaArgs& a, int u, SMem& sm) {
    int w = threadIdx.x >> 6, lane = threadIdx.x & 63;
    int gid = u * 4 + w;                  // (b*H + h)*S + i
    int i = gid & (S_ - 1);
    int bh = gid >> 7;
    int h = bh & (H_ - 1);
    int b = bh >> 3;
    const float* q = a.q;
    const float* k = a.q + BSD_;
    const float* v = a.q + 2 * BSD_;
    const float* qrow = q + (size_t)(b * S_ + i) * D_ + h * DH_;
    sm.at.qsm[w][lane] = qrow[lane];
    __syncthreads();
    float s0 = 0.f, s1 = 0.f;
    const float* k0p = k + (size_t)(b * S_ + lane) * D_ + h * DH_;
    const float* k1p = k0p + (size_t)64 * D_;
#pragma unroll 8
    for (int d = 0; d < DH_; ++d) {
        float qd = sm.at.qsm[w][d];
        s0 += qd * k0p[d];
        s1 += qd * k1p[d];
    }
    s0 *= 0.125f; s1 *= 0.125f;
    float m = fmaxf(s0, s1);
#pragma unroll
    for (int off = 32; off > 0; off >>= 1) m = fmaxf(m, __shfl_xor(m, off));
    float e0 = __expf(s0 - m), e1 = __expf(s1 - m);
    float sum = e0 + e1;
#pragma unroll
    for (int off = 32; off > 0; off >>= 1) sum += __shfl_xor(sum, off);
    float inv = 1.f / sum;
    float p0 = e0 * inv, p1 = e1 * inv;
    float* arow = a.attn + (size_t)gid * S_;
    arow[lane] = p0;
    arow[lane + 64] = p1;
    sm.at.psm[w][lane] = p0;
    sm.at.psm[w][lane + 64] = p1;
    __syncthreads();
    const float* vbase = v + (size_t)b * S_ * D_ + h * DH_ + lane;
    float acc = 0.f;
    for (int j = 0; j < S_; ++j) acc += sm.at.psm[w][j] * vbase[(size_t)j * D_];
    unsigned short sh, sl;
    split2(acc, sh, sl);
    size_t o = (size_t)(b * S_ + i) * D_ + h * DH_ + lane;
    a.ctx_h[o] = sh; a.ctx_l[o] = sl;
}

__device__ void do_adjc(const MegaArgs& a, int u) {
    int idx = u * 256 + threadIdx.x;      // (b*S + i)*S + j
    int j = idx & (S_ - 1);
    int bi = idx >> 7;
    int i = bi & (S_ - 1);
    int b = bi >> 7;
    float s = 0.f;
#pragma unroll
    for (int h = 0; h < H_; ++h) s += a.attn[(((size_t)(b * H_ + h)) * S_ + i) * S_ + j];
    s *= (1.0f / H_);
    if (s > 0.1f && i != j) {
        int p = atomicAdd(a.ecount, 1);
        a.elist[p] = idx;
    }
}

__device__ void do_reduce4(const MegaArgs& a, int u) {
    int base = u * 1024 + threadIdx.x * 4;
    f32x4 s = *(const f32x4*)&a.b2[base & (D_ - 1)];
#pragma unroll
    for (int z = 0; z < 4; ++z) s += *(const f32x4*)&a.part4[(size_t)z * BSD_ + base];
    *(f32x4*)&a.nu[base] = s;
    ushort4v hv, lv;
#pragma unroll
    for (int i = 0; i < 4; ++i) { unsigned short h, l; split2(s[i], h, l); hv[i] = h; lv[i] = l; }
    *(ushort4v*)&a.nu_h[base] = hv;
    *(ushort4v*)&a.nu_l[base] = lv;
}

__device__ void do_reduce8(const MegaArgs& a, int u) {
    int base = u * 1024 + threadIdx.x * 4;
    f32x4 s = *(const f32x4*)&a.nu[base];
#pragma unroll
    for (int z = 0; z < 8; ++z) s += *(const f32x4*)&a.part8[(size_t)z * BSD_ + base];
    ushort4v hv, lv;
#pragma unroll
    for (int i = 0; i < 4; ++i) { unsigned short h, l; split2(s[i], h, l); hv[i] = h; lv[i] = l; }
    *(ushort4v*)&a.rs_h[base] = hv;
    *(ushort4v*)&a.rs_l[base] = lv;
}

__device__ void do_edge(const MegaArgs& a) {
    int w = threadIdx.x >> 6, lane = threadIdx.x & 63;
    int n = *a.ecount;
    const float* b_part = a.apart + BSD_;
    for (int e = blockIdx.x * 4 + w; e < n; e += NBLK * 4) {
        int idx = a.elist[e];
        int vv = idx & (S_ - 1);
        int bu = idx >> 7;
        int u = bu & (S_ - 1);
        int b = bu >> 7;
        const float* ap = a.apart + (size_t)(b * S_ + u) * D_;
        const float* bp = b_part + (size_t)(b * S_ + vv) * D_;
        float lp[R_];
#pragma unroll
        for (int r = 0; r < R_; ++r) lp[r] = 0.f;
#pragma unroll
        for (int jj = 0; jj < D_ / 64; ++jj) {
            int d = lane + jj * 64;
            float hv = fmaxf(ap[d] + bp[d] + a.rc_b1[d], 0.f);
#pragma unroll
            for (int r = 0; r < R_; ++r) lp[r] += hv * a.rc_w2[d * R_ + r];
        }
#pragma unroll
        for (int r = 0; r < R_; ++r) {
#pragma unroll
            for (int off = 32; off > 0; off >>= 1) lp[r] += __shfl_down(lp[r], off);
        }
        if (lane == 0) {
            float best = lp[0] + a.rc_b2[0];
            int bi = 0;
#pragma unroll
            for (int r = 1; r < R_; ++r) {
                float L = lp[r] + a.rc_b2[r];
                if (L > best) { best = L; bi = r; }
            }
            a.rel[idx] = bi;
        }
    }
}

__device__ void do_mbuild(const MegaArgs& a, int u, SMem& sm) {
    int vv = u & (S_ - 1);
    int b = u >> 7;
    int t = threadIdx.x;                 // 256
    for (int i = t; i < R_ * D_; i += 256) sm.mb.acc[i] = 0.f;
    if (t < S_) sm.mb.rl[t] = a.rel[((size_t)b * S_ + t) * S_ + vv];
    __syncthreads();
    for (int uu = 0; uu < S_; ++uu) {
        int r = sm.mb.rl[uu];
        if (r > 0) {
            const float* nurow = a.nu + (size_t)(b * S_ + uu) * D_;
            float* arow = sm.mb.acc + r * D_;
            arow[t] += nurow[t];
            arow[t + 256] += nurow[t + 256];
        }
    }
    __syncthreads();
    unsigned short* Hrow = a.mb_h + (size_t)u * (R_ * D_);
    unsigned short* Lrow = a.mb_l + (size_t)u * (R_ * D_);
    for (int i = t; i < R_ * D_; i += 256) {
        unsigned short sh, sl;
        split2(sm.mb.acc[i], sh, sl);
        Hrow[i] = sh; Lrow[i] = sl;
    }
}

__device__ void do_ln2row(const MegaArgs& a, int row, SMem& sm) {
    int t = threadIdx.x;
    float v0 = a.x[(size_t)row * D_ + t]       + a.y[(size_t)row * D_ + t];
    float v1 = a.x[(size_t)row * D_ + t + 256] + a.y[(size_t)row * D_ + t + 256];
    sm.red[t] = v0 + v1;
    __syncthreads();
    for (int off = 128; off > 0; off >>= 1) { if (t < off) sm.red[t] += sm.red[t + off]; __syncthreads(); }
    float mean = sm.red[0] * (1.0f / D_);
    __syncthreads();
    float d0 = v0 - mean, d1 = v1 - mean;
    sm.red[t] = d0 * d0 + d1 * d1;
    __syncthreads();
    for (int off = 128; off > 0; off >>= 1) { if (t < off) sm.red[t] += sm.red[t + off]; __syncthreads(); }
    float rs = rsqrtf(sm.red[0] * (1.0f / D_) + 1e-5f);
    a.outp[(size_t)row * D_ + t]       = d0 * rs * a.ln2_g[t]       + a.ln2_b[t];
    a.outp[(size_t)row * D_ + t + 256] = d1 * rs * a.ln2_g[t + 256] + a.ln2_b[t + 256];
}

// ---------------- the megakernel ----------------
__global__ __launch_bounds__(256, 2) void mega_kernel(MegaArgs a) {
    __shared__ SMem sm;
    const int bid = blockIdx.x;
    int phase = 0;

    // S0: weight transpose+split (5888 units) + LN1 (512 rows)
    for (int u = bid; u < 5888 + BS_; u += NBLK) {
        if (u < 5888) do_transpose(a, u, sm);
        else          do_ln1row(a, u - 5888, sm);
        __syncthreads();
    }
    grid_barrier(a.flags, a.gen, ++phase);

    // S1: QKV (192 tiles)
    for (int u = bid; u < 192; u += NBLK) {
        int z = u >> 6, r = u & 63;
        const float* bias = (z == 0) ? a.bq : (z == 1) ? a.bk : a.bv;
        do_gemm_tile(a.xn_h, a.xn_l, a.qkv_h + (size_t)z * E_, a.qkv_l + (size_t)z * E_,
                     bias, a.q + (size_t)z * BSD_, nullptr, nullptr,
                     D_, D_, 0, 16, 0, (r >> 3) * 64, (r & 7) * 64, &sm.g);
    }
    grid_barrier(a.flags, a.gen, ++phase);

    // S2: attention (1024 units)
    for (int u = bid; u < 1024; u += NBLK) { do_attn(a, u, sm); __syncthreads(); }
    grid_barrier(a.flags, a.gen, ++phase);

    // S3: adjacency (256 units) || Wo GEMM (64 tiles)
    for (int u = bid; u < 320; u += NBLK) {
        if (u < 256) do_adjc(a, u);
        else {
            int r = u - 256;
            do_gemm_tile(a.ctx_h, a.ctx_l, a.wo_h, a.wo_l, a.bo, nullptr, a.ao_h, a.ao_l,
                         D_, D_, 0, 16, 0, (r >> 3) * 64, (r & 7) * 64, &sm.g);
        }
    }
    grid_barrier(a.flags, a.gen, ++phase);

    // S4: FFN1 relu (256 tiles)
    for (int u = bid; u < 256; u += NBLK)
        do_gemm_tile(a.ao_h, a.ao_l, a.w1_h, a.w1_l, a.b1, nullptr, a.hid_h, a.hid_l,
                     F_, D_, 0, 16, 1, (u >> 5) * 64, (u & 31) * 64, &sm.g);
    grid_barrier(a.flags, a.gen, ++phase);

    // S5: FFN2 split-K=4 partial slabs (256 tiles)
    for (int u = bid; u < 256; u += NBLK) {
        int z = u >> 6, r = u & 63;
        do_gemm_tile(a.hid_h, a.hid_l, a.w2_h, a.w2_l, nullptr, a.part4 + (size_t)z * BSD_,
                     nullptr, nullptr, D_, F_, z * 512, 16, 0, (r >> 3) * 64, (r & 7) * 64, &sm.g);
    }
    grid_barrier(a.flags, a.gen, ++phase);

    // S6: reduce4 + bias -> nu fp32 + h/l
    for (int u = bid; u < 256; u += NBLK) do_reduce4(a, u);
    grid_barrier(a.flags, a.gen, ++phase);

    // S7: rc halves (128 tiles)
    for (int u = bid; u < 128; u += NBLK) {
        int z = u >> 6, r = u & 63;
        do_gemm_tile(a.nu_h, a.nu_l, a.rc_h + (size_t)z * E_, a.rc_l + (size_t)z * E_,
                     nullptr, a.apart + (size_t)z * BSD_, nullptr, nullptr,
                     D_, D_, 0, 16, 0, (r >> 3) * 64, (r & 7) * 64, &sm.g);
    }
    grid_barrier(a.flags, a.gen, ++phase);

    // S8: relation classifier over compacted edges
    do_edge(a);
    grid_barrier(a.flags, a.gen, ++phase);

    // S9: RGCN aggregate (512 units)
    for (int u = bid; u < 512; u += NBLK) { do_mbuild(a, u, sm); __syncthreads(); }
    grid_barrier(a.flags, a.gen, ++phase);

    // S10: kg split-K=8 partial slabs (512 tiles)
    for (int u = bid; u < 512; u += NBLK) {
        int z = u >> 6, r = u & 63;
        do_gemm_tile(a.mb_h, a.mb_l, a.kg_h, a.kg_l, nullptr, a.part8 + (size_t)z * BSD_,
                     nullptr, nullptr, D_, R_ * D_, z * 512, 16, 0, (r >> 3) * 64, (r & 7) * 64, &sm.g);
    }
    grid_barrier(a.flags, a.gen, ++phase);

    // S11: reduce8 + residual -> reasoned h/l
    for (int u = bid; u < 256; u += NBLK) do_reduce8(a, u);
    grid_barrier(a.flags, a.gen, ++phase);

    // S12: s2n (64 tiles)
    for (int u = bid; u < 64; u += NBLK)
        do_gemm_tile(a.rs_h, a.rs_l, a.s2_h, a.s2_l, a.s2n_b, a.y, nullptr, nullptr,
                     D_, D_, 0, 16, 0, (u >> 3) * 64, (u & 7) * 64, &sm.g);
    grid_barrier(a.flags, a.gen, ++phase);

    // S13: LN2 -> out
    for (int u = bid; u < BS_; u += NBLK) { do_ln2row(a, u, sm); __syncthreads(); }
}

extern "C" void kernel_launch(void* const* d_in, const int* in_sizes, int n_in,
                              void* d_out, int out_size, void* d_ws, size_t ws_size,
                              hipStream_t stream) {
    const float* x     = (const float*)d_in[0];
    const float* ln1_g = (const float*)d_in[1];
    const float* ln1_b = (const float*)d_in[2];
    const float* wq    = (const float*)d_in[3];
    const float* bq    = (const float*)d_in[4];
    const float* wk    = (const float*)d_in[5];
    const float* bk    = (const float*)d_in[6];
    const float* wv    = (const float*)d_in[7];
    const float* bv    = (const float*)d_in[8];
    const float* wo    = (const float*)d_in[9];
    const float* bo    = (const float*)d_in[10];
    const float* w1    = (const float*)d_in[11];
    const float* b1    = (const float*)d_in[12];
    const float* w2    = (const float*)d_in[13];
    const float* b2    = (const float*)d_in[14];
    const float* rc_w1 = (const float*)d_in[15];
    const float* rc_b1 = (const float*)d_in[16];
    const float* rc_w2 = (const float*)d_in[17];
    const float* rc_b2 = (const float*)d_in[18];
    const float* kg_w  = (const float*)d_in[19];
    const float* s2n_w = (const float*)d_in[20];
    const float* s2n_b = (const float*)d_in[21];
    const float* ln2_g = (const float*)d_in[22];
    const float* ln2_b = (const float*)d_in[23];

    MegaArgs a;
    a.x = x; a.ln1_g = ln1_g; a.ln1_b = ln1_b;
    a.bq = bq; a.bk = bk; a.bv = bv; a.bo = bo; a.b1 = b1; a.b2 = b2;
    a.rc_b1 = rc_b1; a.rc_w2 = rc_w2; a.rc_b2 = rc_b2; a.s2n_b = s2n_b;
    a.ln2_g = ln2_g; a.ln2_b = ln2_b;
    a.outp = (float*)d_out;

    // ---- workspace layout ----
    unsigned short* wt = (unsigned short*)d_ws;
    unsigned short* qkv_h = wt;
    unsigned short* qkv_l = wt + 3 * E_;
    unsigned short* wo_h  = wt + 6 * E_;
    unsigned short* wo_l  = wt + 7 * E_;
    unsigned short* w1_h  = wt + 8 * E_;
    unsigned short* w1_l  = wt + 12 * E_;
    unsigned short* w2_h  = wt + 16 * E_;
    unsigned short* w2_l  = wt + 20 * E_;
    unsigned short* rc_h  = wt + 24 * E_;
    unsigned short* rc_l  = wt + 26 * E_;
    unsigned short* kg_h  = wt + 28 * E_;
    unsigned short* kg_l  = wt + 36 * E_;
    unsigned short* s2_h  = wt + 44 * E_;
    unsigned short* s2_l  = wt + 45 * E_;
    a.qkv_h = qkv_h; a.qkv_l = qkv_l; a.wo_h = wo_h; a.wo_l = wo_l;
    a.w1_h = w1_h; a.w1_l = w1_l; a.w2_h = w2_h; a.w2_l = w2_l;
    a.rc_h = rc_h; a.rc_l = rc_l; a.kg_h = kg_h; a.kg_l = kg_l;
    a.s2_h = s2_h; a.s2_l = s2_l;

    a.xn_h  = wt + 46 * E_;
    a.xn_l  = a.xn_h + BSD_;
    a.ctx_h = a.xn_l + BSD_;
    a.ctx_l = a.ctx_h + BSD_;
    a.ao_h  = a.ctx_l + BSD_;
    a.ao_l  = a.ao_h + BSD_;
    a.hid_h = a.ao_l + BSD_;
    a.hid_l = a.hid_h + (size_t)BS_ * F_;
    a.nu_h  = a.hid_l + (size_t)BS_ * F_;
    a.nu_l  = a.nu_h + BSD_;
    a.mb_h  = a.nu_l + BSD_;
    a.mb_l  = a.mb_h + (size_t)BS_ * R_ * D_;
    a.rs_h  = a.mb_l + (size_t)BS_ * R_ * D_;
    a.rs_l  = a.rs_h + BSD_;

    float* fbase = (float*)(a.rs_l + BSD_);
    a.attn  = fbase;                          // B*H*S*S = 2097152
    a.q     = a.attn + 2097152;               // q,k,v slabs (3*BSD)
    a.apart = a.q + 3 * BSD_;                 // a_part,b_part (2*BSD)
    a.nu    = a.apart + 2 * BSD_;
    a.y     = a.nu + BSD_;
    a.part4 = a.y + BSD_;                     // 4*BSD
    a.part8 = a.part4 + 4 * BSD_;             // 8*BSD

    int* rel    = (int*)(a.part8 + 8 * BSD_);
    int* ecount = rel + B_ * S_ * S_;
    int* flags  = ecount + 64;
    int* gen    = flags + NBLK * 16;
    int* elist  = gen + 16;
    a.rel = rel; a.ecount = ecount; a.flags = flags; a.gen = gen; a.elist = elist;

    // transpose descriptors (compile-time tile offsets)
    int off = 0;
    auto setd = [&](int i, const float* s, unsigned short* h, unsigned short* l, int K, int N) {
        a.td[i] = TDesc{s, h, l, K, N, off};
        off += (K / 32) * (N / 32);
    };
    setd(0, wq, qkv_h,          qkv_l,          D_, D_);
    setd(1, wk, qkv_h + E_,     qkv_l + E_,     D_, D_);
    setd(2, wv, qkv_h + 2 * E_, qkv_l + 2 * E_, D_, D_);
    setd(3, wo, wo_h, wo_l, D_, D_);
    setd(4, w1, w1_h, w1_l, D_, F_);
    setd(5, w2, w2_h, w2_l, F_, D_);
    setd(6, rc_w1,            rc_h,      rc_l,      D_, D_);
    setd(7, rc_w1 + D_ * D_,  rc_h + E_, rc_l + E_, D_, D_);
    setd(8, kg_w, kg_h, kg_l, R_ * D_, D_);
    setd(9, s2n_w, s2_h, s2_l, D_, D_);

    // zero rel + ecount + barrier flags + gen (contiguous)
    hipMemsetAsync(rel, 0, (size_t)(B_ * S_ * S_ + 64 + NBLK * 16 + 16) * sizeof(int), stream);
    hipLaunchKernelGGL(mega_kernel, dim3(NBLK), dim3(256), 0, stream, a);
}

// Round 3
// 252.548 us; speedup vs baseline: 4.0525x; 4.0525x over previous
//
#include <hip/hip_runtime.h>
#include <hip/hip_bf16.h>

#define B_ 4
#define S_ 128
#define D_ 512
#define H_ 8
#define DH_ 64
#define F_ 2048
#define R_ 8
#define BS_ (B_ * S_)
#define BSD_ (BS_ * D_)
#define E_ 262144          // 512*512

typedef __attribute__((ext_vector_type(8))) short short8;
typedef __attribute__((ext_vector_type(4))) float f32x4;
typedef __attribute__((ext_vector_type(4))) unsigned short ushort4v;

// fp32 -> bf16 hi (RNE) + bf16 lo (RNE of exact residual)
__device__ __forceinline__ void split2(float a, unsigned short& h, unsigned short& l) {
    unsigned u = __float_as_uint(a);
    unsigned hr = (u + 0x7FFFu + ((u >> 16) & 1u)) >> 16;
    h = (unsigned short)hr;
    float lo = a - __uint_as_float(hr << 16);
    unsigned u2 = __float_as_uint(lo);
    l = (unsigned short)((u2 + 0x7FFFu + ((u2 >> 16) & 1u)) >> 16);
}

#define RP 40   // LDS row pitch in ushorts (32 + 8 pad)

struct GemmLds {                       // double-buffered: [buf][hi/lo][row][col]
    unsigned short A[2][2][64][RP];
    unsigned short B[2][2][64][RP];
};                                     // 40960 bytes

// ---------------- prep: weight transpose+split (blocks < nt) + LN1 (rest) ----------------
struct TDesc { const float* s; unsigned short* h; unsigned short* l; int K; int N; int off; };
struct TPack { TDesc d[10]; };

__global__ void prep_kernel(TPack p, int nt, const float* __restrict__ x,
                            const float* __restrict__ g, const float* __restrict__ be,
                            unsigned short* __restrict__ xh, unsigned short* __restrict__ xl) {
    __shared__ float tr[32][33];
    __shared__ float red[256];
    int bid = blockIdx.x;
    if (bid < nt) {
        int wi = 0;
#pragma unroll
        for (int i = 1; i < 10; ++i) if (bid >= p.d[i].off) wi = i;
        const TDesc dd = p.d[wi];
        int t = bid - dd.off;
        int ntk = dd.K / 32;
        int tk = t % ntk, tn = t / ntk;
        int k0 = tk * 32, n0 = tn * 32;
        int col = threadIdx.x & 31, rg = threadIdx.x >> 5;   // rg 0..7
#pragma unroll
        for (int i = 0; i < 4; ++i) {
            int row = rg * 4 + i;
            tr[row][col] = dd.s[(size_t)(k0 + row) * dd.N + n0 + col];
        }
        __syncthreads();
#pragma unroll
        for (int i = 0; i < 4; ++i) {
            int n = n0 + rg * 4 + i;
            int k = k0 + col;
            unsigned short h, l;
            split2(tr[col][rg * 4 + i], h, l);
            dd.h[(size_t)n * dd.K + k] = h;
            dd.l[(size_t)n * dd.K + k] = l;
        }
    } else {
        int row = bid - nt;
        int t = threadIdx.x;
        const float* xr = x + (size_t)row * D_;
        float v0 = xr[t], v1 = xr[t + 256];
        red[t] = v0 + v1;
        __syncthreads();
        for (int off = 128; off > 0; off >>= 1) { if (t < off) red[t] += red[t + off]; __syncthreads(); }
        float mean = red[0] * (1.0f / D_);
        __syncthreads();
        float d0 = v0 - mean, d1 = v1 - mean;
        red[t] = d0 * d0 + d1 * d1;
        __syncthreads();
        for (int off = 128; off > 0; off >>= 1) { if (t < off) red[t] += red[t + off]; __syncthreads(); }
        float rs = rsqrtf(red[0] * (1.0f / D_) + 1e-5f);
        float o0 = d0 * rs * g[t] + be[t];
        float o1 = d1 * rs * g[t + 256] + be[t + 256];
        unsigned short h, l;
        split2(o0, h, l); xh[(size_t)row * D_ + t] = h;       xl[(size_t)row * D_ + t] = l;
        split2(o1, h, l); xh[(size_t)row * D_ + t + 256] = h; xl[(size_t)row * D_ + t + 256] = l;
    }
}

// ---------------- MFMA bf16x3 GEMM core: double-buffered LDS + register prefetch ----------------
__device__ __forceinline__ void mgemm_core(const unsigned short* __restrict__ Ath,
                                           const unsigned short* __restrict__ Atl,
                                           const unsigned short* __restrict__ Bth,
                                           const unsigned short* __restrict__ Btl,
                                           int K, int rowBase, int colBase,
                                           int kStart, int nsteps,
                                           f32x4 acc[2][2], GemmLds* L) {
    int tid = threadIdx.x;
    int w = tid >> 6, lane = tid & 63;
    int lm = lane & 15, quad = lane >> 4;
    int wm = (w & 1) * 32, wn = (w >> 1) * 32;
    int rS = tid >> 2, kcS = (tid & 3) * 8;
    size_t aoff = (size_t)(rowBase + rS) * K + kStart + kcS;
    size_t boff = (size_t)(colBase + rS) * K + kStart + kcS;
    short8 rah = *(const short8*)&Ath[aoff];
    short8 ral = *(const short8*)&Atl[aoff];
    short8 rbh = *(const short8*)&Bth[boff];
    short8 rbl = *(const short8*)&Btl[boff];
    for (int s = 0; s < nsteps; ++s) {
        int p = s & 1;
        *(short8*)&L->A[p][0][rS][kcS] = rah;
        *(short8*)&L->A[p][1][rS][kcS] = ral;
        *(short8*)&L->B[p][0][rS][kcS] = rbh;
        *(short8*)&L->B[p][1][rS][kcS] = rbl;
        __syncthreads();
        if (s + 1 < nsteps) {       // prefetch next k-step; latency hides under ds_read+MFMA
            size_t ao = aoff + (size_t)(s + 1) * 32;
            size_t bo = boff + (size_t)(s + 1) * 32;
            rah = *(const short8*)&Ath[ao];
            ral = *(const short8*)&Atl[ao];
            rbh = *(const short8*)&Bth[bo];
            rbl = *(const short8*)&Btl[bo];
        }
        short8 ah[2], al[2], bh[2], bl[2];
#pragma unroll
        for (int t = 0; t < 2; ++t) {
            ah[t] = *(const short8*)&L->A[p][0][wm + t * 16 + lm][quad * 8];
            al[t] = *(const short8*)&L->A[p][1][wm + t * 16 + lm][quad * 8];
            bh[t] = *(const short8*)&L->B[p][0][wn + t * 16 + lm][quad * 8];
            bl[t] = *(const short8*)&L->B[p][1][wn + t * 16 + lm][quad * 8];
        }
#pragma unroll
        for (int tm = 0; tm < 2; ++tm)
#pragma unroll
            for (int tn = 0; tn < 2; ++tn) {
                acc[tm][tn] = __builtin_amdgcn_mfma_f32_16x16x32_bf16(ah[tm], bh[tn], acc[tm][tn], 0, 0, 0);
                acc[tm][tn] = __builtin_amdgcn_mfma_f32_16x16x32_bf16(ah[tm], bl[tn], acc[tm][tn], 0, 0, 0);
                acc[tm][tn] = __builtin_amdgcn_mfma_f32_16x16x32_bf16(al[tm], bh[tn], acc[tm][tn], 0, 0, 0);
            }
    }
}

// Generic GEMM: optional fp32 out, optional pre-split bf16 h/l out.
__global__ __launch_bounds__(256) void mgemm_kernel(const unsigned short* __restrict__ Ath,
                                                    const unsigned short* __restrict__ Atl,
                                                    const unsigned short* __restrict__ Bth,
                                                    const unsigned short* __restrict__ Btl,
                                                    const float* __restrict__ bias,
                                                    float* __restrict__ Cf,
                                                    unsigned short* __restrict__ Ch,
                                                    unsigned short* __restrict__ Cl,
                                                    int N, int K, int relu) {
    __shared__ GemmLds L;
    int tid = threadIdx.x;
    int w = tid >> 6, lane = tid & 63;
    int lm = lane & 15, quad = lane >> 4;
    int wm = (w & 1) * 32, wn = (w >> 1) * 32;
    int rowBase = blockIdx.y * 64, colBase = blockIdx.x * 64;
    f32x4 acc[2][2] = {};
    mgemm_core(Ath, Atl, Bth, Btl, K, rowBase, colBase, 0, K / 32, acc, &L);
#pragma unroll
    for (int tm = 0; tm < 2; ++tm)
#pragma unroll
        for (int tn = 0; tn < 2; ++tn) {
            int col = colBase + wn + tn * 16 + lm;
            float bi = bias ? bias[col] : 0.f;
#pragma unroll
            for (int r = 0; r < 4; ++r) {
                int row = rowBase + wm + tm * 16 + quad * 4 + r;
                float v = acc[tm][tn][r] + bi;
                if (relu) v = fmaxf(v, 0.f);
                size_t o = (size_t)row * N + col;
                if (Cf) Cf[o] = v;
                if (Ch) {
                    unsigned short sh, sl;
                    split2(v, sh, sl);
                    Ch[o] = sh; Cl[o] = sl;
                }
            }
        }
}

// z-batched GEMM over weight slabs (QKV: 3, rc halves: 2); fp32 out only.
__global__ __launch_bounds__(256) void mgemm_zw_kernel(const unsigned short* __restrict__ Ath,
                                                       const unsigned short* __restrict__ Atl,
                                                       const unsigned short* __restrict__ Bth,
                                                       const unsigned short* __restrict__ Btl,
                                                       const float* __restrict__ b0,
                                                       const float* __restrict__ b1,
                                                       const float* __restrict__ b2,
                                                       float* __restrict__ Cbase,
                                                       int M, int N, int K) {
    __shared__ GemmLds L;
    int z = blockIdx.z;
    const unsigned short* bth = Bth + (size_t)z * K * N;
    const unsigned short* btl = Btl + (size_t)z * K * N;
    const float* bias = (z == 0) ? b0 : (z == 1) ? b1 : b2;
    float* C = Cbase + (size_t)z * M * N;
    int tid = threadIdx.x;
    int w = tid >> 6, lane = tid & 63;
    int lm = lane & 15, quad = lane >> 4;
    int wm = (w & 1) * 32, wn = (w >> 1) * 32;
    int rowBase = blockIdx.y * 64, colBase = blockIdx.x * 64;
    f32x4 acc[2][2] = {};
    mgemm_core(Ath, Atl, bth, btl, K, rowBase, colBase, 0, K / 32, acc, &L);
#pragma unroll
    for (int tm = 0; tm < 2; ++tm)
#pragma unroll
        for (int tn = 0; tn < 2; ++tn) {
            int col = colBase + wn + tn * 16 + lm;
            float bi = bias ? bias[col] : 0.f;
#pragma unroll
            for (int r = 0; r < 4; ++r) {
                int row = rowBase + wm + tm * 16 + quad * 4 + r;
                C[(size_t)row * N + col] = acc[tm][tn][r] + bi;
            }
        }
}

// split-K partial GEMM: each z-slice writes its own fp32 slab (no atomics).
__global__ __launch_bounds__(256) void mgemm_part_kernel(const unsigned short* __restrict__ Ath,
                                                         const unsigned short* __restrict__ Atl,
                                                         const unsigned short* __restrict__ Bth,
                                                         const unsigned short* __restrict__ Btl,
                                                         float* __restrict__ Cbase,
                                                         int M, int N, int K) {
    __shared__ GemmLds L;
    int ks = gridDim.z, z = blockIdx.z;
    int kLen = K / ks, kStart = z * kLen;
    float* C = Cbase + (size_t)z * M * N;
    int tid = threadIdx.x;
    int w = tid >> 6, lane = tid & 63;
    int lm = lane & 15, quad = lane >> 4;
    int wm = (w & 1) * 32, wn = (w >> 1) * 32;
    int rowBase = blockIdx.y * 64, colBase = blockIdx.x * 64;
    f32x4 acc[2][2] = {};
    mgemm_core(Ath, Atl, Bth, Btl, K, rowBase, colBase, kStart, kLen / 32, acc, &L);
#pragma unroll
    for (int tm = 0; tm < 2; ++tm)
#pragma unroll
        for (int tn = 0; tn < 2; ++tn) {
            int col = colBase + wn + tn * 16 + lm;
#pragma unroll
            for (int r = 0; r < 4; ++r) {
                int row = rowBase + wm + tm * 16 + quad * 4 + r;
                C[(size_t)row * N + col] = acc[tm][tn][r];
            }
        }
}

// sum 4 partials + bias -> nu fp32 + bf16 h/l
__global__ void reduce4_kernel(const float* __restrict__ part, const float* __restrict__ b2,
                               float* __restrict__ nu,
                               unsigned short* __restrict__ nh, unsigned short* __restrict__ nl) {
    int base = blockIdx.x * 1024 + threadIdx.x * 4;
    f32x4 s = *(const f32x4*)&b2[base & (D_ - 1)];
#pragma unroll
    for (int z = 0; z < 4; ++z) s += *(const f32x4*)&part[(size_t)z * BSD_ + base];
    *(f32x4*)&nu[base] = s;
    ushort4v hv, lv;
#pragma unroll
    for (int i = 0; i < 4; ++i) { unsigned short h, l; split2(s[i], h, l); hv[i] = h; lv[i] = l; }
    *(ushort4v*)&nh[base] = hv;
    *(ushort4v*)&nl[base] = lv;
}

// reasoned = nu + sum 8 partials -> bf16 h/l only
__global__ void reduce8_kernel(const float* __restrict__ part, const float* __restrict__ nu,
                               unsigned short* __restrict__ rh, unsigned short* __restrict__ rl) {
    int base = blockIdx.x * 1024 + threadIdx.x * 4;
    f32x4 s = *(const f32x4*)&nu[base];
#pragma unroll
    for (int z = 0; z < 8; ++z) s += *(const f32x4*)&part[(size_t)z * BSD_ + base];
    ushort4v hv, lv;
#pragma unroll
    for (int i = 0; i < 4; ++i) { unsigned short h, l; split2(s[i], h, l); hv[i] = h; lv[i] = l; }
    *(ushort4v*)&rh[base] = hv;
    *(ushort4v*)&rl[base] = lv;
}

// ---------------- Fused attention + adjacency: one block per (b,i), 8 waves = 8 heads ----------------
__global__ __launch_bounds__(512) void attn_fused_kernel(const float* __restrict__ q,
                                                         const float* __restrict__ k,
                                                         const float* __restrict__ v,
                                                         unsigned short* __restrict__ ch,
                                                         unsigned short* __restrict__ cl,
                                                         int* __restrict__ ecount,
                                                         int* __restrict__ elist) {
    __shared__ float qsm[H_][DH_];
    __shared__ float psm[H_][S_];
    int h = threadIdx.x >> 6, lane = threadIdx.x & 63;
    int blk = blockIdx.x;                 // b*S + i
    int i = blk & (S_ - 1);
    int b = blk >> 7;
    const float* qrow = q + (size_t)(b * S_ + i) * D_ + h * DH_;
    qsm[h][lane] = qrow[lane];
    __syncthreads();
    // two scores per lane: j = lane, lane+64
    float s0 = 0.f, s1 = 0.f;
    const float* k0p = k + (size_t)(b * S_ + lane) * D_ + h * DH_;
    const float* k1p = k0p + (size_t)64 * D_;
#pragma unroll 8
    for (int d = 0; d < DH_; ++d) {
        float qd = qsm[h][d];
        s0 += qd * k0p[d];
        s1 += qd * k1p[d];
    }
    s0 *= 0.125f; s1 *= 0.125f;
    float m = fmaxf(s0, s1);
#pragma unroll
    for (int off = 32; off > 0; off >>= 1) m = fmaxf(m, __shfl_xor(m, off));
    float e0 = __expf(s0 - m), e1 = __expf(s1 - m);
    float sum = e0 + e1;
#pragma unroll
    for (int off = 32; off > 0; off >>= 1) sum += __shfl_xor(sum, off);
    float inv = 1.f / sum;
    psm[h][lane] = e0 * inv;
    psm[h][lane + 64] = e1 * inv;
    __syncthreads();
    // adjacency: threads 0..127 handle j = tid
    if (threadIdx.x < S_) {
        int j = threadIdx.x;
        float s = 0.f;
#pragma unroll
        for (int hh = 0; hh < H_; ++hh) s += psm[hh][j];
        s *= (1.0f / H_);
        if (s > 0.1f && i != j) {
            int p = atomicAdd(ecount, 1);
            elist[p] = blk * S_ + j;
        }
    }
    // ctx: lane = d within this head
    const float* vbase = v + (size_t)b * S_ * D_ + h * DH_ + lane;
    float acc = 0.f;
    for (int j = 0; j < S_; ++j) acc += psm[h][j] * vbase[(size_t)j * D_];
    unsigned short sh, sl;
    split2(acc, sh, sl);
    size_t o = (size_t)(b * S_ + i) * D_ + h * DH_ + lane;
    ch[o] = sh; cl[o] = sl;
}

// ---------------- Relation classifier over compacted edges ----------------
__global__ __launch_bounds__(64) void edge_kernel(const float* __restrict__ a_part,
                                                  const float* __restrict__ b_part,
                                                  const float* __restrict__ rc_b1,
                                                  const float* __restrict__ rc_w2,
                                                  const float* __restrict__ rc_b2,
                                                  const int* __restrict__ elist,
                                                  const int* __restrict__ ecount,
                                                  int* __restrict__ rel) {
    int lane = threadIdx.x;
    int n = *ecount;
    for (int e = blockIdx.x; e < n; e += gridDim.x) {
        int idx = elist[e];
        int vv = idx & (S_ - 1);
        int bu = idx >> 7;
        int u = bu & (S_ - 1);
        int b = bu >> 7;
        const float* ap = a_part + (size_t)(b * S_ + u) * D_;
        const float* bp = b_part + (size_t)(b * S_ + vv) * D_;
        float lp[R_];
#pragma unroll
        for (int r = 0; r < R_; ++r) lp[r] = 0.f;
#pragma unroll
        for (int jj = 0; jj < D_ / 64; ++jj) {
            int d = lane + jj * 64;
            float hv = fmaxf(ap[d] + bp[d] + rc_b1[d], 0.f);
#pragma unroll
            for (int r = 0; r < R_; ++r) lp[r] += hv * rc_w2[d * R_ + r];
        }
#pragma unroll
        for (int r = 0; r < R_; ++r) {
#pragma unroll
            for (int off = 32; off > 0; off >>= 1) lp[r] += __shfl_down(lp[r], off);
        }
        if (lane == 0) {
            float best = lp[0] + rc_b2[0];
            int bi = 0;
#pragma unroll
            for (int r = 1; r < R_; ++r) {
                float L = lp[r] + rc_b2[r];
                if (L > best) { best = L; bi = r; }
            }
            rel[idx] = bi;
        }
    }
}

// ---------------- mbuild: LDS accumulate, pre-split write ----------------
__global__ __launch_bounds__(128) void mbuild_kernel(const float* __restrict__ nu,
                                                     const int* __restrict__ rel,
                                                     unsigned short* __restrict__ Mh,
                                                     unsigned short* __restrict__ Ml) {
    __shared__ float acc[R_ * D_];   // 16 KB
    __shared__ int rl[S_];
    int blk = blockIdx.x;            // b*S + v
    int vv = blk & (S_ - 1);
    int b = blk >> 7;
    int t = threadIdx.x;             // 128
    for (int i = t; i < R_ * D_; i += 128) acc[i] = 0.f;
    rl[t] = rel[((size_t)b * S_ + t) * S_ + vv];
    __syncthreads();
    for (int u = 0; u < S_; ++u) {
        int r = rl[u];
        if (r > 0) {
            const float* nurow = nu + (size_t)(b * S_ + u) * D_;
            float* arow = acc + r * D_;
#pragma unroll
            for (int jj = 0; jj < D_ / 128; ++jj) arow[t + jj * 128] += nurow[t + jj * 128];
        }
    }
    __syncthreads();
    unsigned short* Hrow = Mh + (size_t)blk * (R_ * D_);
    unsigned short* Lrow = Ml + (size_t)blk * (R_ * D_);
    for (int i = t; i < R_ * D_; i += 128) {
        unsigned short sh, sl;
        split2(acc[i], sh, sl);
        Hrow[i] = sh; Lrow[i] = sl;
    }
}

// ---------------- LayerNorm 2 -> fp32 out ----------------
__global__ void ln2_kernel(const float* __restrict__ x, const float* __restrict__ y,
                           const float* __restrict__ g, const float* __restrict__ be,
                           float* __restrict__ out) {
    int row = blockIdx.x;
    int t = threadIdx.x;
    __shared__ float red[256];
    float v0 = x[row * D_ + t]       + y[row * D_ + t];
    float v1 = x[row * D_ + t + 256] + y[row * D_ + t + 256];
    red[t] = v0 + v1;
    __syncthreads();
    for (int off = 128; off > 0; off >>= 1) {
        if (t < off) red[t] += red[t + off];
        __syncthreads();
    }
    float mean = red[0] * (1.0f / D_);
    __syncthreads();
    float d0 = v0 - mean, d1 = v1 - mean;
    red[t] = d0 * d0 + d1 * d1;
    __syncthreads();
    for (int off = 128; off > 0; off >>= 1) {
        if (t < off) red[t] += red[t + off];
        __syncthreads();
    }
    float rs = rsqrtf(red[0] * (1.0f / D_) + 1e-5f);
    out[row * D_ + t]       = d0 * rs * g[t]       + be[t];
    out[row * D_ + t + 256] = d1 * rs * g[t + 256] + be[t + 256];
}

extern "C" void kernel_launch(void* const* d_in, const int* in_sizes, int n_in,
                              void* d_out, int out_size, void* d_ws, size_t ws_size,
                              hipStream_t stream) {
    const float* x     = (const float*)d_in[0];
    const float* ln1_g = (const float*)d_in[1];
    const float* ln1_b = (const float*)d_in[2];
    const float* wq    = (const float*)d_in[3];
    const float* bq    = (const float*)d_in[4];
    const float* wk    = (const float*)d_in[5];
    const float* bk    = (const float*)d_in[6];
    const float* wv    = (const float*)d_in[7];
    const float* bv    = (const float*)d_in[8];
    const float* wo    = (const float*)d_in[9];
    const float* bo    = (const float*)d_in[10];
    const float* w1    = (const float*)d_in[11];
    const float* b1    = (const float*)d_in[12];
    const float* w2    = (const float*)d_in[13];
    const float* b2    = (const float*)d_in[14];
    const float* rc_w1 = (const float*)d_in[15];
    const float* rc_b1 = (const float*)d_in[16];
    const float* rc_w2 = (const float*)d_in[17];
    const float* rc_b2 = (const float*)d_in[18];
    const float* kg_w  = (const float*)d_in[19];
    const float* s2n_w = (const float*)d_in[20];
    const float* s2n_b = (const float*)d_in[21];
    const float* ln2_g = (const float*)d_in[22];
    const float* ln2_b = (const float*)d_in[23];
    float* out = (float*)d_out;

    const int BS  = BS_;              // 512
    const int BSD = BSD_;             // 262144

    // ---- Workspace layout ----
    unsigned short* wt = (unsigned short*)d_ws;
    unsigned short* qkv_h = wt;
    unsigned short* qkv_l = wt + 3 * E_;
    unsigned short* wo_h  = wt + 6 * E_;
    unsigned short* wo_l  = wt + 7 * E_;
    unsigned short* w1_h  = wt + 8 * E_;
    unsigned short* w1_l  = wt + 12 * E_;
    unsigned short* w2_h  = wt + 16 * E_;
    unsigned short* w2_l  = wt + 20 * E_;
    unsigned short* rc_h  = wt + 24 * E_;
    unsigned short* rc_l  = wt + 26 * E_;
    unsigned short* kg_h  = wt + 28 * E_;
    unsigned short* kg_l  = wt + 36 * E_;
    unsigned short* s2_h  = wt + 44 * E_;
    unsigned short* s2_l  = wt + 45 * E_;

    // activation bf16 h/l buffers
    unsigned short* xn_h  = wt + 46 * E_;
    unsigned short* xn_l  = xn_h + BSD;
    unsigned short* ctx_h = xn_l + BSD;
    unsigned short* ctx_l = ctx_h + BSD;
    unsigned short* ao_h  = ctx_l + BSD;
    unsigned short* ao_l  = ao_h + BSD;
    unsigned short* hid_h = ao_l + BSD;              // BS*F
    unsigned short* hid_l = hid_h + (size_t)BS * F_;
    unsigned short* nu_h  = hid_l + (size_t)BS * F_;
    unsigned short* nu_l  = nu_h + BSD;
    unsigned short* mb_h  = nu_l + BSD;              // BS*R*D
    unsigned short* mb_l  = mb_h + (size_t)BS * R_ * D_;
    unsigned short* rs_h  = mb_l + (size_t)BS * R_ * D_;
    unsigned short* rs_l  = rs_h + BSD;

    float* fbase  = (float*)(rs_l + BSD);
    float* q      = fbase;                           // q,k,v slabs (3*BSD)
    float* v_     = q + 2 * BSD;
    float* apart  = q + 3 * BSD;                     // a_part,b_part
    float* nu     = apart + 2 * BSD;
    float* y      = nu + BSD;
    float* part4  = y + BSD;                         // 4*BSD
    float* part8  = part4 + 4 * BSD;                 // 8*BSD

    int* rel    = (int*)(part8 + 8 * BSD);
    int* ecount = rel + B_ * S_ * S_;
    int* elist  = ecount + 64;

    // 0a. zero rel + ecount
    hipMemsetAsync(rel, 0, (size_t)(B_ * S_ * S_ + 64) * 4, stream);
    // 0b. transpose+split all weights + LN1 (fused)
    TPack tp;
    int off = 0;
    auto setd = [&](int i, const float* s, unsigned short* h, unsigned short* l, int K, int N) {
        tp.d[i] = TDesc{s, h, l, K, N, off};
        off += (K / 32) * (N / 32);
    };
    setd(0, wq, qkv_h,          qkv_l,          D_, D_);
    setd(1, wk, qkv_h + E_,     qkv_l + E_,     D_, D_);
    setd(2, wv, qkv_h + 2 * E_, qkv_l + 2 * E_, D_, D_);
    setd(3, wo, wo_h, wo_l, D_, D_);
    setd(4, w1, w1_h, w1_l, D_, F_);
    setd(5, w2, w2_h, w2_l, F_, D_);
    setd(6, rc_w1,            rc_h,      rc_l,      D_, D_);
    setd(7, rc_w1 + D_ * D_,  rc_h + E_, rc_l + E_, D_, D_);
    setd(8, kg_w, kg_h, kg_l, R_ * D_, D_);
    setd(9, s2n_w, s2_h, s2_l, D_, D_);
    hipLaunchKernelGGL(prep_kernel, dim3(off + BS), dim3(256), 0, stream, tp, off,
                       x, ln1_g, ln1_b, xn_h, xn_l);

    // 2. QKV (z-batched) -> q,k,v fp32
    hipLaunchKernelGGL(mgemm_zw_kernel, dim3(D_ / 64, BS / 64, 3), dim3(256), 0, stream,
                       xn_h, xn_l, qkv_h, qkv_l, bq, bk, bv, q, BS, D_, D_);
    // 3. attention + adjacency (fused) -> ctx h/l, elist
    hipLaunchKernelGGL(attn_fused_kernel, dim3(BS), dim3(512), 0, stream,
                       q, q + BSD, v_, ctx_h, ctx_l, ecount, elist);
    // 5. wo: ctx -> attn_out h/l
    hipLaunchKernelGGL(mgemm_kernel, dim3(D_ / 64, BS / 64), dim3(256), 0, stream,
                       ctx_h, ctx_l, wo_h, wo_l, bo, (float*)nullptr, ao_h, ao_l, D_, D_, 0);
    // 6. FFN1 (relu): attn_out -> hidden h/l
    hipLaunchKernelGGL(mgemm_kernel, dim3(F_ / 64, BS / 64), dim3(256), 0, stream,
                       ao_h, ao_l, w1_h, w1_l, b1, (float*)nullptr, hid_h, hid_l, F_, D_, 1);
    // 7. FFN2 split-K=4 partials
    hipLaunchKernelGGL(mgemm_part_kernel, dim3(D_ / 64, BS / 64, 4), dim3(256), 0, stream,
                       hid_h, hid_l, w2_h, w2_l, part4, BS, D_, F_);
    // 7b. reduce + bias -> nu fp32 + h/l
    hipLaunchKernelGGL(reduce4_kernel, dim3(BSD / 1024), dim3(256), 0, stream,
                       part4, b2, nu, nu_h, nu_l);
    // 8. rc halves (z-batched) -> a_part,b_part fp32
    hipLaunchKernelGGL(mgemm_zw_kernel, dim3(D_ / 64, BS / 64, 2), dim3(256), 0, stream,
                       nu_h, nu_l, rc_h, rc_l, (const float*)nullptr, (const float*)nullptr,
                       (const float*)nullptr, apart, BS, D_, D_);
    // 9. edges (persistent over compacted list)
    hipLaunchKernelGGL(edge_kernel, dim3(256), dim3(64), 0, stream,
                       apart, apart + BSD, rc_b1, rc_w2, rc_b2, elist, ecount, rel);
    // 10. RGCN aggregate -> Mbuf h/l
    hipLaunchKernelGGL(mbuild_kernel, dim3(BS), dim3(128), 0, stream, nu, rel, mb_h, mb_l);
    // 11. Mbuf @ kg_w split-K=8 partials
    hipLaunchKernelGGL(mgemm_part_kernel, dim3(D_ / 64, BS / 64, 8), dim3(256), 0, stream,
                       mb_h, mb_l, kg_h, kg_l, part8, BS, D_, R_ * D_);
    // 11b. reduce + residual (nu) -> reasoned h/l
    hipLaunchKernelGGL(reduce8_kernel, dim3(BSD / 1024), dim3(256), 0, stream,
                       part8, nu, rs_h, rs_l);
    // 13. s2n: reasoned -> y fp32
    hipLaunchKernelGGL(mgemm_kernel, dim3(D_ / 64, BS / 64), dim3(256), 0, stream,
                       rs_h, rs_l, s2_h, s2_l, s2n_b, y, (unsigned short*)nullptr,
                       (unsigned short*)nullptr, D_, D_, 0);
    // 14. LN2 -> out
    hipLaunchKernelGGL(ln2_kernel, dim3(BS), dim3(256), 0, stream, x, y, ln2_g, ln2_b, out);
}